// Round 1
// baseline (820.556 us; speedup 1.0000x reference)
//
#include <hip/hip_runtime.h>

typedef _Float16 f16;
typedef _Float16 f16x8 __attribute__((ext_vector_type(8)));
typedef _Float16 f16x4 __attribute__((ext_vector_type(4)));
typedef float    f32x4 __attribute__((ext_vector_type(4)));

#define N_TOK   100000
#define NPAD    100032         // 1563 * 64
#define NT1     1563
#define CDIM    512
#define KSTEPS  (NPAD/32)      // 3126
#define K2BLK   128

// ---------------- workspace layout (bytes) ----------------
#define O_WT     ((size_t)0)                       // w^T fp16 [512][NPAD]
#define SZ_WT    ((size_t)512*NPAD*2)
#define O_YT     (O_WT + SZ_WT)                    // y^T fp16 [64][NPAD]
#define SZ_YT    ((size_t)64*NPAD*2)
#define O_WS16   (O_YT + SZ_YT)                    // w_slice fp16 [512][512]
#define SZ_WS16  ((size_t)512*512*2)
#define O_W116   (O_WS16 + SZ_WS16)                // w1 fp16 [64][512]
#define SZ_W116  ((size_t)64*512*2)
#define O_SPP    (O_W116 + SZ_W116)                // s_pre partials [128][32768] f32
#define SZ_SPP   ((size_t)K2BLK*32768*4)
#define O_DPP    (O_SPP + SZ_SPP)                  // d partials [128][512] f32
#define SZ_DPP   ((size_t)K2BLK*512*4)
#define O_SPRE   (O_DPP + SZ_DPP)                  // s_pre [512][64] f32
#define SZ_SPRE  ((size_t)32768*4)
#define O_DSTD   (O_SPRE + SZ_SPRE)                // d [512] f32
#define SZ_DSTD  ((size_t)512*4)
#define O_SOUT   (O_DSTD + SZ_DSTD)                // s_out^T fp16 [8][64dh][64m]

// ---------------- K0: weight conversion ----------------
__global__ void k0_convert(const float* __restrict__ wsf, const float* __restrict__ w1f,
                           f16* __restrict__ ws16, f16* __restrict__ w116) {
    int i = blockIdx.x * 256 + threadIdx.x;
    if (i < 512*512) ws16[i] = (f16)wsf[i];
    if (i < 64*512)  w116[i] = (f16)w1f[i];
}

// ---------------- K1: slice GEMM + softmax + y GEMM ----------------
// block = 256 threads (4 waves), one 64-row n-tile per block.
// LDS: A (x fp16, frag-linear, 64KB) aliased with W^T [512][68]; Y^T [64][68] after.
__launch_bounds__(256, 2)
__global__ void k1_slice(const float* __restrict__ x, const float* __restrict__ temperature,
                         const f16* __restrict__ ws16, const float* __restrict__ bsl,
                         const f16* __restrict__ w116,
                         f16* __restrict__ wT, f16* __restrict__ yT) {
    __shared__ char smem[(512*68 + 64*68) * 2];      // 78,336 B
    f16* ldsA = (f16*)smem;                           // [4096 chunks][8 f16]
    f16* ldsW = (f16*)smem;                           // [512][68]
    f16* ldsY = (f16*)(smem + (size_t)512*68*2);      // [64][68]

    const int tid  = threadIdx.x;
    const int wave = tid >> 6;
    const int lane = tid & 63;
    const int quad = lane >> 4;
    const int col  = lane & 15;
    const int n0   = blockIdx.x * 64;
    const int e0   = wave * 128;

    // ---- stage x tile (64 x 512) fp32 -> fp16 into frag-linear LDS ----
    // chunk c: L=c&63, t=(c>>6)&3, kg=c>>8 holds x[n0+t*16+(L&15)][kg*32+(L>>4)*8 .. +8]
    for (int i = 0; i < 16; ++i) {
        int c = tid + i * 256;
        int L = c & 63, t = (c >> 6) & 3, kg = c >> 8;
        int nr = n0 + t * 16 + (L & 15);
        if (nr > N_TOK - 1) nr = N_TOK - 1;
        int k = kg * 32 + (L >> 4) * 8;
        const float* src = x + (size_t)nr * CDIM + k;
        float4 a = *(const float4*)(src);
        float4 b = *(const float4*)(src + 4);
        f16x8 h;
        h[0]=(f16)a.x; h[1]=(f16)a.y; h[2]=(f16)a.z; h[3]=(f16)a.w;
        h[4]=(f16)b.x; h[5]=(f16)b.y; h[6]=(f16)b.z; h[7]=(f16)b.w;
        *(f16x8*)(ldsA + (size_t)c * 8) = h;
    }
    __syncthreads();

    // ---- GEMM1: logits (64n x 128e per wave, K=512); GEMM-y (64n x 16d per wave) ----
    f32x4 acc1[4][8];
    f32x4 acc2[4];
    #pragma unroll
    for (int t = 0; t < 4; ++t) {
        #pragma unroll
        for (int u = 0; u < 8; ++u) acc1[t][u] = f32x4{0.f,0.f,0.f,0.f};
        acc2[t] = f32x4{0.f,0.f,0.f,0.f};
    }

    #pragma unroll 4
    for (int kg = 0; kg < 16; ++kg) {
        f16x8 af[4];
        #pragma unroll
        for (int t = 0; t < 4; ++t)
            af[t] = *(const f16x8*)(ldsA + ((size_t)(kg*4 + t)*64 + lane) * 8);
        int kofs = kg * 32 + quad * 8;
        #pragma unroll
        for (int u = 0; u < 8; ++u) {
            f16x8 bf = *(const f16x8*)(ws16 + (size_t)(e0 + u*16 + col) * CDIM + kofs);
            #pragma unroll
            for (int t = 0; t < 4; ++t)
                acc1[t][u] = __builtin_amdgcn_mfma_f32_16x16x32_f16(af[t], bf, acc1[t][u], 0, 0, 0);
        }
        f16x8 by = *(const f16x8*)(w116 + (size_t)(wave*16 + col) * CDIM + kofs);
        #pragma unroll
        for (int t = 0; t < 4; ++t)
            acc2[t] = __builtin_amdgcn_mfma_f32_16x16x32_f16(af[t], by, acc2[t], 0, 0, 0);
    }

    // ---- bias + temperature ----
    #pragma unroll
    for (int u = 0; u < 8; ++u) {
        float b = bsl[e0 + u*16 + col];
        #pragma unroll
        for (int t = 0; t < 4; ++t)
            #pragma unroll
            for (int r = 0; r < 4; ++r) acc1[t][u][r] += b;
    }
    float invt[2];
    #pragma unroll
    for (int hh = 0; hh < 2; ++hh) {
        float tv = temperature[wave*2 + hh];
        tv = fminf(fmaxf(tv, 0.1f), 5.0f);
        invt[hh] = 1.0f / tv;
    }

    __syncthreads();   // all waves done reading ldsA; ldsW may now overwrite it

    // ---- softmax over M=64 per head, fully in-register (quad = 16-lane row group) ----
    #pragma unroll
    for (int t = 0; t < 4; ++t) {
        #pragma unroll
        for (int hh = 0; hh < 2; ++hh) {
            float mx[4];
            #pragma unroll
            for (int r = 0; r < 4; ++r) {
                float m01 = fmaxf(acc1[t][hh*4+0][r], acc1[t][hh*4+1][r]);
                float m23 = fmaxf(acc1[t][hh*4+2][r], acc1[t][hh*4+3][r]);
                mx[r] = fmaxf(m01, m23);
            }
            #pragma unroll
            for (int d = 1; d < 16; d <<= 1)
                #pragma unroll
                for (int r = 0; r < 4; ++r) mx[r] = fmaxf(mx[r], __shfl_xor(mx[r], d));
            float sm[4] = {0.f, 0.f, 0.f, 0.f};
            #pragma unroll
            for (int uu = 0; uu < 4; ++uu)
                #pragma unroll
                for (int r = 0; r < 4; ++r) {
                    float ev = __expf((acc1[t][hh*4+uu][r] - mx[r]) * invt[hh]);
                    acc1[t][hh*4+uu][r] = ev;
                    sm[r] += ev;
                }
            #pragma unroll
            for (int d = 1; d < 16; d <<= 1)
                #pragma unroll
                for (int r = 0; r < 4; ++r) sm[r] += __shfl_xor(sm[r], d);
            #pragma unroll
            for (int r = 0; r < 4; ++r) sm[r] = 1.0f / sm[r];
            #pragma unroll
            for (int uu = 0; uu < 4; ++uu) {
                f16x4 pk;
                #pragma unroll
                for (int r = 0; r < 4; ++r) {
                    int n = n0 + t*16 + quad*4 + r;
                    float wv = (n < N_TOK) ? acc1[t][hh*4+uu][r] * sm[r] : 0.0f;
                    pk[r] = (f16)wv;
                }
                int e = e0 + (hh*4 + uu)*16 + col;
                *(f16x4*)(ldsW + (size_t)e*68 + t*16 + quad*4) = pk;
            }
        }
    }

    // ---- y epilogue -> ldsY [d][n] transposed ----
    {
        int d = wave*16 + col;
        #pragma unroll
        for (int t = 0; t < 4; ++t) {
            f16x4 pk;
            #pragma unroll
            for (int r = 0; r < 4; ++r) {
                int n = n0 + t*16 + quad*4 + r;
                pk[r] = (n < N_TOK) ? (f16)acc2[t][r] : (f16)0.f;
            }
            *(f16x4*)(ldsY + (size_t)d*68 + t*16 + quad*4) = pk;
        }
    }
    __syncthreads();

    // ---- coalesced global stores: w^T rows and y^T rows ----
    for (int i = 0; i < 32; ++i) {
        int id = tid + i*256;                 // 8192 = 512 rows x 16 chunks(4 f16)
        int e = id >> 4, p = id & 15;
        f16x4 v = *(const f16x4*)(ldsW + (size_t)e*68 + p*4);
        *(f16x4*)(wT + (size_t)e*NPAD + n0 + p*4) = v;
    }
    for (int i = 0; i < 4; ++i) {
        int id = tid + i*256;                 // 1024 = 64 rows x 16 chunks
        int d = id >> 4, p = id & 15;
        f16x4 v = *(const f16x4*)(ldsY + (size_t)d*68 + p*4);
        *(f16x4*)(yT + (size_t)d*NPAD + n0 + p*4) = v;
    }
}

// ---------------- K2: s_pre = sum_n w[n,e]*y[n,d]  (split-K, disjoint partials) ----------------
__launch_bounds__(256, 2)
__global__ void k2_spre(const f16* __restrict__ wT, const f16* __restrict__ yT,
                        float* __restrict__ spp, float* __restrict__ dpp) {
    const int tid = threadIdx.x, wave = tid >> 6, lane = tid & 63;
    const int quad = lane >> 4, col = lane & 15;
    f32x4 acc[8][4];
    float dac[8];
    #pragma unroll
    for (int u = 0; u < 8; ++u) {
        dac[u] = 0.f;
        #pragma unroll
        for (int v = 0; v < 4; ++v) acc[u][v] = f32x4{0.f,0.f,0.f,0.f};
    }
    for (int ks = blockIdx.x; ks < KSTEPS; ks += K2BLK) {
        int nb = ks*32 + quad*8;
        f16x8 bf[4];
        #pragma unroll
        for (int v = 0; v < 4; ++v)
            bf[v] = *(const f16x8*)(yT + (size_t)(v*16 + col)*NPAD + nb);
        #pragma unroll
        for (int u = 0; u < 8; ++u) {
            f16x8 af = *(const f16x8*)(wT + (size_t)(wave*128 + u*16 + col)*NPAD + nb);
            #pragma unroll
            for (int v = 0; v < 4; ++v)
                acc[u][v] = __builtin_amdgcn_mfma_f32_16x16x32_f16(af, bf[v], acc[u][v], 0, 0, 0);
            float s = 0.f;
            #pragma unroll
            for (int j = 0; j < 8; ++j) s += (float)af[j];
            dac[u] += s;
        }
    }
    #pragma unroll
    for (int u = 0; u < 8; ++u) {
        dac[u] += __shfl_xor(dac[u], 16);
        dac[u] += __shfl_xor(dac[u], 32);
    }
    if (quad == 0) {
        #pragma unroll
        for (int u = 0; u < 8; ++u)
            dpp[blockIdx.x*512 + wave*128 + u*16 + col] = dac[u];
    }
    float* dst = spp + (size_t)blockIdx.x * 32768;
    #pragma unroll
    for (int u = 0; u < 8; ++u)
        #pragma unroll
        for (int v = 0; v < 4; ++v)
            *(f32x4*)(dst + ((size_t)((wave*8 + u)*4 + v)*64 + lane)*4) = acc[u][v];
}

// ---------------- K2r: reduce partials, de-swizzle frag order ----------------
__global__ void k2r_reduce(const float* __restrict__ spp, const float* __restrict__ dpp,
                           float* __restrict__ spre, float* __restrict__ dstd) {
    int i = blockIdx.x*256 + threadIdx.x;   // 32768
    float s = 0.f;
    for (int p = 0; p < K2BLK; ++p) s += spp[(size_t)p*32768 + i];
    int r = i & 3, L = (i >> 2) & 63, v = (i >> 8) & 3, u = (i >> 10) & 7, w = i >> 13;
    int e = w*128 + u*16 + (L >> 4)*4 + r;
    int d = v*16 + (L & 15);
    spre[e*64 + d] = s;
    if (i < 512) {
        float t = 0.f;
        for (int p = 0; p < K2BLK; ++p) t += dpp[p*512 + i];
        dstd[i] = t;
    }
}

// ---------------- K3: per-head middle block (exact fp32) ----------------
__global__ void k3_attn(const float* __restrict__ spre, const float* __restrict__ dstd,
                        const float* __restrict__ b1, const float* __restrict__ wq,
                        const float* __restrict__ wk, const float* __restrict__ wv,
                        const float* __restrict__ w3, const float* __restrict__ b3,
                        f16* __restrict__ sout) {
    __shared__ float ss[64][65], qq[64][65], kk[64][65], vv[64][65], sc[64][65], sa[64][65];
    const int h = blockIdx.x, tid = threadIdx.x;
    for (int i = tid; i < 4096; i += 256) {
        int m = i >> 6, d = i & 63;
        ss[m][d] = spre[(h*64 + m)*64 + d] / (dstd[h*64 + m] + 1e-5f) + b1[d];
    }
    __syncthreads();
    for (int i = tid; i < 4096; i += 256) {
        int m = i >> 6, e = i & 63;
        float aq = 0.f, ak = 0.f, av = 0.f;
        for (int d = 0; d < 64; ++d) {
            float sv = ss[m][d];
            aq += sv * wq[e*64 + d];
            ak += sv * wk[e*64 + d];
            av += sv * wv[e*64 + d];
        }
        qq[m][e] = aq; kk[m][e] = ak; vv[m][e] = av;
    }
    __syncthreads();
    for (int i = tid; i < 4096; i += 256) {
        int m = i >> 6, l = i & 63;
        float a = 0.f;
        for (int e = 0; e < 64; ++e) a += qq[m][e] * kk[l][e];
        sc[m][l] = a * 0.125f;
    }
    __syncthreads();
    if (tid < 64) {
        int m = tid;
        float mx = -1e30f;
        for (int l = 0; l < 64; ++l) mx = fmaxf(mx, sc[m][l]);
        float sm = 0.f;
        for (int l = 0; l < 64; ++l) { float ev = __expf(sc[m][l] - mx); sc[m][l] = ev; sm += ev; }
        float rs = 1.0f / sm;
        for (int l = 0; l < 64; ++l) sc[m][l] *= rs;
    }
    __syncthreads();
    for (int i = tid; i < 4096; i += 256) {
        int m = i >> 6, e = i & 63;
        float a = 0.f;
        for (int l = 0; l < 64; ++l) a += sc[m][l] * vv[l][e];
        sa[m][e] = a;
    }
    __syncthreads();
    for (int i = tid; i < 4096; i += 256) {
        int m = i >> 6, d = i & 63;
        float a = b3[d];
        for (int e = 0; e < 64; ++e) a += sa[m][e] * w3[d*64 + e];
        sout[(h*64 + d)*64 + m] = (f16)a;    // transposed: [h][dh][m]
    }
}

// ---------------- K4: deslice x_out = w @ s_out ----------------
__launch_bounds__(256, 2)
__global__ void k4_deslice(const f16* __restrict__ wT, const f16* __restrict__ sout,
                           float* __restrict__ out) {
    __shared__ f16 ldsW[512*68];
    const int tid = threadIdx.x, wave = tid >> 6, lane = tid & 63;
    const int quad = lane >> 4, col = lane & 15;
    const int n0 = blockIdx.x * 64;

    for (int i = 0; i < 32; ++i) {
        int id = tid + i*256;               // 8192 = 512 rows x 16 chunks
        int e = id >> 4, p = id & 15;
        f16x4 v = *(const f16x4*)(wT + (size_t)e*NPAD + n0 + p*4);
        *(f16x4*)(ldsW + (size_t)e*68 + p*4) = v;
    }
    __syncthreads();

    f32x4 acc[2][4][4];
    #pragma unroll
    for (int hh = 0; hh < 2; ++hh)
        #pragma unroll
        for (int t = 0; t < 4; ++t)
            #pragma unroll
            for (int v = 0; v < 4; ++v) acc[hh][t][v] = f32x4{0.f,0.f,0.f,0.f};

    #pragma unroll
    for (int hh = 0; hh < 2; ++hh) {
        int h = wave*2 + hh;
        #pragma unroll
        for (int ks = 0; ks < 2; ++ks) {
            f16x8 af[4];
            #pragma unroll
            for (int t = 0; t < 4; ++t) {
                f16x8 a;
                #pragma unroll
                for (int j = 0; j < 8; ++j)
                    a[j] = ldsW[(size_t)(h*64 + ks*32 + quad*8 + j)*68 + t*16 + col];
                af[t] = a;
            }
            #pragma unroll
            for (int v = 0; v < 4; ++v) {
                f16x8 bf = *(const f16x8*)(sout + (size_t)(h*64 + v*16 + col)*64 + ks*32 + quad*8);
                #pragma unroll
                for (int t = 0; t < 4; ++t)
                    acc[hh][t][v] = __builtin_amdgcn_mfma_f32_16x16x32_f16(af[t], bf, acc[hh][t][v], 0, 0, 0);
            }
        }
    }

    #pragma unroll
    for (int hh = 0; hh < 2; ++hh) {
        int h = wave*2 + hh;
        #pragma unroll
        for (int t = 0; t < 4; ++t)
            #pragma unroll
            for (int v = 0; v < 4; ++v)
                #pragma unroll
                for (int r = 0; r < 4; ++r) {
                    int n = n0 + t*16 + quad*4 + r;
                    if (n < N_TOK)
                        out[(size_t)n*512 + h*64 + v*16 + col] = acc[hh][t][v][r];
                }
    }
}

// ---------------- launcher ----------------
extern "C" void kernel_launch(void* const* d_in, const int* in_sizes, int n_in,
                              void* d_out, int out_size, void* d_ws, size_t ws_size,
                              hipStream_t stream) {
    const float* x           = (const float*)d_in[0];
    const float* temperature = (const float*)d_in[1];
    const float* w_slice     = (const float*)d_in[2];
    const float* b_slice     = (const float*)d_in[3];
    const float* w1          = (const float*)d_in[4];
    const float* b1          = (const float*)d_in[5];
    const float* wq          = (const float*)d_in[6];
    const float* wk          = (const float*)d_in[7];
    const float* wv          = (const float*)d_in[8];
    const float* w3          = (const float*)d_in[9];
    const float* b3          = (const float*)d_in[10];
    float* out = (float*)d_out;
    char*  ws  = (char*)d_ws;

    f16*   wT    = (f16*)(ws + O_WT);
    f16*   yT    = (f16*)(ws + O_YT);
    f16*   ws16  = (f16*)(ws + O_WS16);
    f16*   w116  = (f16*)(ws + O_W116);
    float* spp   = (float*)(ws + O_SPP);
    float* dpp   = (float*)(ws + O_DPP);
    float* spre  = (float*)(ws + O_SPRE);
    float* dstd  = (float*)(ws + O_DSTD);
    f16*   sout  = (f16*)(ws + O_SOUT);

    k0_convert<<<1024, 256, 0, stream>>>(w_slice, w1, ws16, w116);
    k1_slice<<<NT1, 256, 0, stream>>>(x, temperature, ws16, b_slice, w116, wT, yT);
    k2_spre<<<K2BLK, 256, 0, stream>>>(wT, yT, spp, dpp);
    k2r_reduce<<<128, 256, 0, stream>>>(spp, dpp, spre, dstd);
    k3_attn<<<8, 256, 0, stream>>>(spre, dstd, b1, wq, wk, wv, w3, b3, sout);
    k4_deslice<<<NT1, 256, 0, stream>>>(wT, sout, out);
}

// Round 2
// 770.019 us; speedup vs baseline: 1.0656x; 1.0656x over previous
//
#include <hip/hip_runtime.h>

typedef _Float16 f16;
typedef _Float16 f16x8 __attribute__((ext_vector_type(8)));
typedef _Float16 f16x4 __attribute__((ext_vector_type(4)));
typedef float    f32x4 __attribute__((ext_vector_type(4)));

#define N_TOK   100000
#define NPAD    100032         // 3126 * 32 = 1563 * 64
#define NT1     3126           // k1 tiles (32 rows)
#define NT4     1563           // k4 tiles (64 rows)
#define CDIM    512
#define KSTEPS  (NPAD/32)      // 3126
#define K2SPL   128            // split-K partials

// ---------------- workspace layout (bytes) ----------------
#define O_WT     ((size_t)0)                       // w^T fp16 [512][NPAD]
#define SZ_WT    ((size_t)512*NPAD*2)
#define O_YT     (O_WT + SZ_WT)                    // y^T fp16 [64][NPAD]
#define SZ_YT    ((size_t)64*NPAD*2)
#define O_WS16   (O_YT + SZ_YT)                    // w_slice fp16 [512][512]
#define SZ_WS16  ((size_t)512*512*2)
#define O_W116   (O_WS16 + SZ_WS16)                // w1 fp16 [64][512]
#define SZ_W116  ((size_t)64*512*2)
#define O_SPP    (O_W116 + SZ_W116)                // s_pre partials [128][32768] f32
#define SZ_SPP   ((size_t)K2SPL*32768*4)
#define O_DPP    (O_SPP + SZ_SPP)                  // d partials [128][512] f32
#define SZ_DPP   ((size_t)K2SPL*512*4)
#define O_SPRE   (O_DPP + SZ_DPP)                  // s_pre [512][64] f32
#define SZ_SPRE  ((size_t)32768*4)
#define O_DSTD   (O_SPRE + SZ_SPRE)                // d [512] f32
#define SZ_DSTD  ((size_t)512*4)
#define O_SOUT   (O_DSTD + SZ_DSTD)                // s_out^T fp16 [8][64dh][64m]

// ---------------- K0: weight conversion ----------------
__global__ void k0_convert(const float* __restrict__ wsf, const float* __restrict__ w1f,
                           f16* __restrict__ ws16, f16* __restrict__ w116) {
    int i = blockIdx.x * 256 + threadIdx.x;
    if (i < 512*512) ws16[i] = (f16)wsf[i];
    if (i < 64*512)  w116[i] = (f16)w1f[i];
}

// ---------------- K1: slice GEMM + softmax + y GEMM ----------------
// block = 256 threads (4 waves), one 32-row n-tile per block.
// Each wave: 32n x 128e logits (2 heads) + 32n x 16d y-GEMM.
// LDS: A (x fp16 frag-linear, 32KB) aliased with W^T [512][34] + Y^T [64][34].
__launch_bounds__(256, 3)
__global__ void k1_slice(const float* __restrict__ x, const float* __restrict__ temperature,
                         const f16* __restrict__ ws16, const float* __restrict__ bsl,
                         const f16* __restrict__ w116,
                         f16* __restrict__ wT, f16* __restrict__ yT) {
    __shared__ char smem[(512*34 + 64*34) * 2];      // 39,168 B
    f16* ldsA = (f16*)smem;                           // [2048 chunks][8 f16]
    f16* ldsW = (f16*)smem;                           // [512][34]
    f16* ldsY = (f16*)(smem + (size_t)512*34*2);      // [64][34]

    const int tid  = threadIdx.x;
    const int wave = tid >> 6;
    const int lane = tid & 63;
    const int quad = lane >> 4;
    const int col  = lane & 15;
    const int n0   = blockIdx.x * 32;
    const int e0   = wave * 128;

    // ---- stage x tile (32 x 512) fp32 -> fp16 into frag-linear LDS ----
    // chunk c: L=c&63, t=(c>>6)&1, kg=c>>7 holds x[n0+t*16+(L&15)][kg*32+(L>>4)*8 .. +8]
    #pragma unroll
    for (int i = 0; i < 8; ++i) {
        int c = tid + i * 256;
        int L = c & 63, t = (c >> 6) & 1, kg = c >> 7;
        int nr = n0 + t * 16 + (L & 15);
        if (nr > N_TOK - 1) nr = N_TOK - 1;
        int k = kg * 32 + (L >> 4) * 8;
        const float* src = x + (size_t)nr * CDIM + k;
        float4 a = *(const float4*)(src);
        float4 b = *(const float4*)(src + 4);
        f16x8 h;
        h[0]=(f16)a.x; h[1]=(f16)a.y; h[2]=(f16)a.z; h[3]=(f16)a.w;
        h[4]=(f16)b.x; h[5]=(f16)b.y; h[6]=(f16)b.z; h[7]=(f16)b.w;
        *(f16x8*)(ldsA + (size_t)c * 8) = h;
    }
    __syncthreads();

    // ---- GEMM1: logits (32n x 128e per wave, K=512); GEMM-y (32n x 16d per wave) ----
    f32x4 acc1[2][8];
    f32x4 acc2[2];
    #pragma unroll
    for (int t = 0; t < 2; ++t) {
        #pragma unroll
        for (int u = 0; u < 8; ++u) acc1[t][u] = f32x4{0.f,0.f,0.f,0.f};
        acc2[t] = f32x4{0.f,0.f,0.f,0.f};
    }

    #pragma unroll 2
    for (int kg = 0; kg < 16; ++kg) {
        f16x8 af[2];
        #pragma unroll
        for (int t = 0; t < 2; ++t)
            af[t] = *(const f16x8*)(ldsA + ((size_t)(kg*2 + t)*64 + lane) * 8);
        int kofs = kg * 32 + quad * 8;
        #pragma unroll
        for (int u = 0; u < 8; ++u) {
            f16x8 bf = *(const f16x8*)(ws16 + (size_t)(e0 + u*16 + col) * CDIM + kofs);
            #pragma unroll
            for (int t = 0; t < 2; ++t)
                acc1[t][u] = __builtin_amdgcn_mfma_f32_16x16x32_f16(af[t], bf, acc1[t][u], 0, 0, 0);
        }
        f16x8 by = *(const f16x8*)(w116 + (size_t)(wave*16 + col) * CDIM + kofs);
        #pragma unroll
        for (int t = 0; t < 2; ++t)
            acc2[t] = __builtin_amdgcn_mfma_f32_16x16x32_f16(af[t], by, acc2[t], 0, 0, 0);
    }

    // ---- bias + temperature ----
    #pragma unroll
    for (int u = 0; u < 8; ++u) {
        float b = bsl[e0 + u*16 + col];
        #pragma unroll
        for (int t = 0; t < 2; ++t)
            #pragma unroll
            for (int r = 0; r < 4; ++r) acc1[t][u][r] += b;
    }
    float invt[2];
    #pragma unroll
    for (int hh = 0; hh < 2; ++hh) {
        float tv = temperature[wave*2 + hh];
        tv = fminf(fmaxf(tv, 0.1f), 5.0f);
        invt[hh] = 1.0f / tv;
    }

    __syncthreads();   // all waves done reading ldsA; ldsW may now overwrite it

    // ---- softmax over M=64 per head, in-register (16-lane col groups) ----
    #pragma unroll
    for (int t = 0; t < 2; ++t) {
        #pragma unroll
        for (int hh = 0; hh < 2; ++hh) {
            float mx[4];
            #pragma unroll
            for (int r = 0; r < 4; ++r) {
                float m01 = fmaxf(acc1[t][hh*4+0][r], acc1[t][hh*4+1][r]);
                float m23 = fmaxf(acc1[t][hh*4+2][r], acc1[t][hh*4+3][r]);
                mx[r] = fmaxf(m01, m23);
            }
            #pragma unroll
            for (int d = 1; d < 16; d <<= 1)
                #pragma unroll
                for (int r = 0; r < 4; ++r) mx[r] = fmaxf(mx[r], __shfl_xor(mx[r], d));
            float sm[4] = {0.f, 0.f, 0.f, 0.f};
            #pragma unroll
            for (int uu = 0; uu < 4; ++uu)
                #pragma unroll
                for (int r = 0; r < 4; ++r) {
                    float ev = __expf((acc1[t][hh*4+uu][r] - mx[r]) * invt[hh]);
                    acc1[t][hh*4+uu][r] = ev;
                    sm[r] += ev;
                }
            #pragma unroll
            for (int d = 1; d < 16; d <<= 1)
                #pragma unroll
                for (int r = 0; r < 4; ++r) sm[r] += __shfl_xor(sm[r], d);
            #pragma unroll
            for (int r = 0; r < 4; ++r) sm[r] = 1.0f / sm[r];
            #pragma unroll
            for (int uu = 0; uu < 4; ++uu) {
                f16x4 pk;
                #pragma unroll
                for (int r = 0; r < 4; ++r) {
                    int n = n0 + t*16 + quad*4 + r;
                    float wv = (n < N_TOK) ? acc1[t][hh*4+uu][r] * sm[r] : 0.0f;
                    pk[r] = (f16)wv;
                }
                int e = e0 + (hh*4 + uu)*16 + col;
                *(f16x4*)(ldsW + (size_t)e*34 + t*16 + quad*4) = pk;
            }
        }
    }

    // ---- y epilogue -> ldsY [d][n] transposed ----
    {
        int d = wave*16 + col;
        #pragma unroll
        for (int t = 0; t < 2; ++t) {
            f16x4 pk;
            #pragma unroll
            for (int r = 0; r < 4; ++r) {
                int n = n0 + t*16 + quad*4 + r;
                pk[r] = (n < N_TOK) ? (f16)acc2[t][r] : (f16)0.f;
            }
            *(f16x4*)(ldsY + (size_t)d*34 + t*16 + quad*4) = pk;
        }
    }
    __syncthreads();

    // ---- coalesced global stores: w^T rows and y^T rows ----
    #pragma unroll
    for (int i = 0; i < 16; ++i) {
        int id = tid + i*256;                 // 4096 = 512 rows x 8 chunks(4 f16)
        int e = id >> 3, p = id & 7;
        f16x4 v = *(const f16x4*)(ldsW + (size_t)e*34 + p*4);
        *(f16x4*)(wT + (size_t)e*NPAD + n0 + p*4) = v;
    }
    #pragma unroll
    for (int i = 0; i < 2; ++i) {
        int id = tid + i*256;                 // 512 = 64 rows x 8 chunks
        int d = id >> 3, p = id & 7;
        f16x4 v = *(const f16x4*)(ldsY + (size_t)d*34 + p*4);
        *(f16x4*)(yT + (size_t)d*NPAD + n0 + p*4) = v;
    }
}

// ---------------- K2: s_pre = sum_n w[n,e]*y[n,d]  (split-K x e-half, disjoint partials) ----------------
// grid = 256: bid = slot*2 + ehalf; each block: 256e x 64d, ~24 k-steps.
__launch_bounds__(256, 3)
__global__ void k2_spre(const f16* __restrict__ wT, const f16* __restrict__ yT,
                        float* __restrict__ spp, float* __restrict__ dpp) {
    const int tid = threadIdx.x, wave = tid >> 6, lane = tid & 63;
    const int quad = lane >> 4, col = lane & 15;
    const int slot = blockIdx.x >> 1, ehalf = blockIdx.x & 1;
    const int ebase = ehalf * 256 + wave * 64;

    f32x4 acc[4][4];
    float dac[4];
    #pragma unroll
    for (int u = 0; u < 4; ++u) {
        dac[u] = 0.f;
        #pragma unroll
        for (int v = 0; v < 4; ++v) acc[u][v] = f32x4{0.f,0.f,0.f,0.f};
    }
    for (int ks = slot; ks < KSTEPS; ks += K2SPL) {
        int nb = ks*32 + quad*8;
        f16x8 bf[4];
        #pragma unroll
        for (int v = 0; v < 4; ++v)
            bf[v] = *(const f16x8*)(yT + (size_t)(v*16 + col)*NPAD + nb);
        #pragma unroll
        for (int u = 0; u < 4; ++u) {
            f16x8 af = *(const f16x8*)(wT + (size_t)(ebase + u*16 + col)*NPAD + nb);
            #pragma unroll
            for (int v = 0; v < 4; ++v)
                acc[u][v] = __builtin_amdgcn_mfma_f32_16x16x32_f16(af, bf[v], acc[u][v], 0, 0, 0);
            float s = 0.f;
            #pragma unroll
            for (int j = 0; j < 8; ++j) s += (float)af[j];
            dac[u] += s;
        }
    }
    #pragma unroll
    for (int u = 0; u < 4; ++u) {
        dac[u] += __shfl_xor(dac[u], 16);
        dac[u] += __shfl_xor(dac[u], 32);
    }
    if (quad == 0) {
        #pragma unroll
        for (int u = 0; u < 4; ++u)
            dpp[slot*512 + ebase + u*16 + col] = dac[u];
    }
    // partial layout: [slot][ehalf*16384 + ((wave*4+u)*4+v)*256 + lane*4]
    float* dst = spp + (size_t)slot * 32768 + (size_t)ehalf * 16384;
    #pragma unroll
    for (int u = 0; u < 4; ++u)
        #pragma unroll
        for (int v = 0; v < 4; ++v)
            *(f32x4*)(dst + (size_t)((wave*4 + u)*4 + v)*256 + (size_t)lane*4) = acc[u][v];
}

// ---------------- K2r: reduce partials, de-swizzle frag order ----------------
__global__ void k2r_reduce(const float* __restrict__ spp, const float* __restrict__ dpp,
                           float* __restrict__ spre, float* __restrict__ dstd) {
    int i = blockIdx.x*256 + threadIdx.x;   // 32768
    float s = 0.f;
    for (int p = 0; p < K2SPL; ++p) s += spp[(size_t)p*32768 + i];
    int r = i & 3, L = (i >> 2) & 63, v = (i >> 8) & 3, t = (i >> 10) & 15, eh = i >> 14;
    int e = eh*256 + (t >> 2)*64 + (t & 3)*16 + (L >> 4)*4 + r;
    int d = v*16 + (L & 15);
    spre[e*64 + d] = s;
    if (i < 512) {
        float tt = 0.f;
        for (int p = 0; p < K2SPL; ++p) tt += dpp[p*512 + i];
        dstd[i] = tt;
    }
}

// ---------------- K3: per-head middle block (exact fp32, all-LDS) ----------------
__global__ void k3_attn(const float* __restrict__ spre, const float* __restrict__ dstd,
                        const float* __restrict__ b1, const float* __restrict__ wq,
                        const float* __restrict__ wk, const float* __restrict__ wv,
                        const float* __restrict__ w3, const float* __restrict__ b3,
                        f16* __restrict__ sout) {
    __shared__ float wa[64][65], wb[64][65], wc[64][65];   // wq,wk,wv; wa reused for w3
    __shared__ float ss[64][65], qq[64][65], kk[64][65], vv[64][65], sc[64][65];
    const int h = blockIdx.x, tid = threadIdx.x;

    // stage weights (coalesced) + s
    for (int i = tid; i < 4096; i += 256) {
        int r = i >> 6, c = i & 63;
        wa[r][c] = wq[i];
        wb[r][c] = wk[i];
        wc[r][c] = wv[i];
        ss[r][c] = spre[h*4096 + i] / (dstd[h*64 + r] + 1e-5f) + b1[c];
    }
    __syncthreads();

    // q,k,v: lane-varying index e hits padded rows (bank-conflict-free)
    #pragma unroll
    for (int it = 0; it < 16; ++it) {
        int m = it*4 + (tid >> 6), e = tid & 63;
        float aq = 0.f, ak = 0.f, av = 0.f;
        #pragma unroll 8
        for (int d = 0; d < 64; ++d) {
            float sv = ss[m][d];                // broadcast
            aq += sv * wa[e][d];
            ak += sv * wb[e][d];
            av += sv * wc[e][d];
        }
        qq[m][e] = aq; kk[m][e] = ak; vv[m][e] = av;
    }
    __syncthreads();

    // scores; also stage w3 into wa (wa dead after qkv)
    for (int i = tid; i < 4096; i += 256) wa[i >> 6][i & 63] = w3[i];
    #pragma unroll
    for (int it = 0; it < 16; ++it) {
        int m = it*4 + (tid >> 6), l = tid & 63;
        float a = 0.f;
        #pragma unroll 8
        for (int e = 0; e < 64; ++e) a += qq[m][e] * kk[l][e];
        sc[m][l] = a * 0.125f;
    }
    __syncthreads();

    // softmax rows
    if (tid < 64) {
        int m = tid;
        float mx = -1e30f;
        #pragma unroll 8
        for (int l = 0; l < 64; ++l) mx = fmaxf(mx, sc[m][l]);
        float sm = 0.f;
        #pragma unroll 8
        for (int l = 0; l < 64; ++l) { float ev = __expf(sc[m][l] - mx); sc[m][l] = ev; sm += ev; }
        float rs = 1.0f / sm;
        #pragma unroll 8
        for (int l = 0; l < 64; ++l) sc[m][l] *= rs;
    }
    __syncthreads();

    // s_att -> ss (ss dead after qkv)
    #pragma unroll
    for (int it = 0; it < 16; ++it) {
        int m = it*4 + (tid >> 6), e = tid & 63;
        float a = 0.f;
        #pragma unroll 8
        for (int l = 0; l < 64; ++l) a += sc[m][l] * vv[l][e];   // sc broadcast
        ss[m][e] = a;
    }
    __syncthreads();

    // s_out^T: lanes vary m -> contiguous store; wa[d][e] broadcast
    #pragma unroll
    for (int it = 0; it < 16; ++it) {
        int d = it*4 + (tid >> 6), m = tid & 63;
        float a = b3[d];
        #pragma unroll 8
        for (int e = 0; e < 64; ++e) a += ss[m][e] * wa[d][e];
        sout[(h*64 + d)*64 + m] = (f16)a;
    }
}

// ---------------- K4: deslice x_out = w @ s_out ----------------
__launch_bounds__(256, 2)
__global__ void k4_deslice(const f16* __restrict__ wT, const f16* __restrict__ sout,
                           float* __restrict__ out) {
    __shared__ f16 ldsW[512*68];
    const int tid = threadIdx.x, wave = tid >> 6, lane = tid & 63;
    const int quad = lane >> 4, col = lane & 15;
    const int n0 = blockIdx.x * 64;

    #pragma unroll
    for (int i = 0; i < 32; ++i) {
        int id = tid + i*256;               // 8192 = 512 rows x 16 chunks
        int e = id >> 4, p = id & 15;
        f16x4 v = *(const f16x4*)(wT + (size_t)e*NPAD + n0 + p*4);
        *(f16x4*)(ldsW + (size_t)e*68 + p*4) = v;
    }
    __syncthreads();

    f32x4 acc[2][4][4];
    #pragma unroll
    for (int hh = 0; hh < 2; ++hh)
        #pragma unroll
        for (int t = 0; t < 4; ++t)
            #pragma unroll
            for (int v = 0; v < 4; ++v) acc[hh][t][v] = f32x4{0.f,0.f,0.f,0.f};

    #pragma unroll
    for (int hh = 0; hh < 2; ++hh) {
        int h = wave*2 + hh;
        #pragma unroll
        for (int ks = 0; ks < 2; ++ks) {
            f16x8 af[4];
            #pragma unroll
            for (int t = 0; t < 4; ++t) {
                f16x8 a;
                #pragma unroll
                for (int j = 0; j < 8; ++j)
                    a[j] = ldsW[(size_t)(h*64 + ks*32 + quad*8 + j)*68 + t*16 + col];
                af[t] = a;
            }
            #pragma unroll
            for (int v = 0; v < 4; ++v) {
                f16x8 bf = *(const f16x8*)(sout + (size_t)(h*64 + v*16 + col)*64 + ks*32 + quad*8);
                #pragma unroll
                for (int t = 0; t < 4; ++t)
                    acc[hh][t][v] = __builtin_amdgcn_mfma_f32_16x16x32_f16(af[t], bf, acc[hh][t][v], 0, 0, 0);
            }
        }
    }

    #pragma unroll
    for (int hh = 0; hh < 2; ++hh) {
        int h = wave*2 + hh;
        #pragma unroll
        for (int t = 0; t < 4; ++t)
            #pragma unroll
            for (int v = 0; v < 4; ++v)
                #pragma unroll
                for (int r = 0; r < 4; ++r) {
                    int n = n0 + t*16 + quad*4 + r;
                    if (n < N_TOK)
                        out[(size_t)n*512 + h*64 + v*16 + col] = acc[hh][t][v][r];
                }
    }
}

// ---------------- launcher ----------------
extern "C" void kernel_launch(void* const* d_in, const int* in_sizes, int n_in,
                              void* d_out, int out_size, void* d_ws, size_t ws_size,
                              hipStream_t stream) {
    const float* x           = (const float*)d_in[0];
    const float* temperature = (const float*)d_in[1];
    const float* w_slice     = (const float*)d_in[2];
    const float* b_slice     = (const float*)d_in[3];
    const float* w1          = (const float*)d_in[4];
    const float* b1          = (const float*)d_in[5];
    const float* wq          = (const float*)d_in[6];
    const float* wk          = (const float*)d_in[7];
    const float* wv          = (const float*)d_in[8];
    const float* w3          = (const float*)d_in[9];
    const float* b3          = (const float*)d_in[10];
    float* out = (float*)d_out;
    char*  ws  = (char*)d_ws;

    f16*   wT    = (f16*)(ws + O_WT);
    f16*   yT    = (f16*)(ws + O_YT);
    f16*   ws16  = (f16*)(ws + O_WS16);
    f16*   w116  = (f16*)(ws + O_W116);
    float* spp   = (float*)(ws + O_SPP);
    float* dpp   = (float*)(ws + O_DPP);
    float* spre  = (float*)(ws + O_SPRE);
    float* dstd  = (float*)(ws + O_DSTD);
    f16*   sout  = (f16*)(ws + O_SOUT);

    k0_convert<<<1024, 256, 0, stream>>>(w_slice, w1, ws16, w116);
    k1_slice<<<NT1, 256, 0, stream>>>(x, temperature, ws16, b_slice, w116, wT, yT);
    k2_spre<<<K2SPL*2, 256, 0, stream>>>(wT, yT, spp, dpp);
    k2r_reduce<<<128, 256, 0, stream>>>(spp, dpp, spre, dstd);
    k3_attn<<<8, 256, 0, stream>>>(spre, dstd, b1, wq, wk, wv, w3, b3, sout);
    k4_deslice<<<NT4, 256, 0, stream>>>(wT, sout, out);
}